// Round 14
// baseline (454.852 us; speedup 1.0000x reference)
//
#include <hip/hip_runtime.h>
#include <hip/hip_bf16.h>

#define T_TOK 4096
#define DMODEL 1024
#define DFF 4096
#define NEXP 8
#define ROWS_TOT 8192      // T_TOK * TOPK, fixed
#define ROWS_PAD 8448      // + 256 pad rows for BM=256 tile overrun
#define YSTR ((size_t)ROWS_PAD * DMODEL)

typedef __bf16 bf16x8 __attribute__((ext_vector_type(8)));
typedef float f32x4 __attribute__((ext_vector_type(4)));
typedef unsigned short u16;

__device__ __forceinline__ u16 f2bf(float f) {
    __hip_bfloat16 b = __float2bfloat16(f);
    return __builtin_bit_cast(u16, b);
}
__device__ __forceinline__ float bf2f(u16 u) {
    unsigned v = (unsigned)u << 16;
    return __builtin_bit_cast(float, v);
}

template<int N> __device__ __forceinline__ void vmw() {
    if constexpr (N == 6)      asm volatile("s_waitcnt vmcnt(6)" ::: "memory");
    else if constexpr (N == 4) asm volatile("s_waitcnt vmcnt(4)" ::: "memory");
    else if constexpr (N == 2) asm volatile("s_waitcnt vmcnt(2)" ::: "memory");
    else                       asm volatile("s_waitcnt vmcnt(0)" ::: "memory");
}

// exact-erf GELU via Abramowitz-Stegun 7.1.26 (|eps|<=1.5e-7 << bf16 rounding of h)
__device__ __forceinline__ float fast_gelu(float v) {
    const float x = v * 0.70710678118654752f;
    const float ax = fabsf(x);
    const float t = 1.f / fmaf(0.3275911f, ax, 1.f);
    float p = fmaf(1.061405429f, t, -1.453152027f);
    p = fmaf(p, t, 1.421413741f);
    p = fmaf(p, t, -0.284496736f);
    p = fmaf(p, t, 0.254829592f);
    p *= t;
    const float e = __expf(-ax * ax);
    float erfv = fmaf(-p, e, 1.f);
    erfv = copysignf(erfv, x);
    return 0.5f * v * (1.f + erfv);
}

// ---------------- router: logits, softmax-top2 gates, expert histogram ----------
__global__ void router_kernel(const float* __restrict__ x, const float* __restrict__ Wr,
                              const float* __restrict__ br, int* __restrict__ top_idx,
                              float* __restrict__ gates, int* __restrict__ counts) {
    const int t = blockIdx.x;
    const int lane = threadIdx.x;
    float part[8];
#pragma unroll
    for (int e = 0; e < 8; ++e) part[e] = 0.f;
#pragma unroll
    for (int j = 0; j < 4; ++j) {
        const int d0 = j * 256 + lane * 4;
        const float4 xv = *(const float4*)(x + (size_t)t * DMODEL + d0);
        const float xs[4] = {xv.x, xv.y, xv.z, xv.w};
#pragma unroll
        for (int i = 0; i < 4; ++i) {
            const float4 w0 = *(const float4*)(Wr + (d0 + i) * 8);
            const float4 w1 = *(const float4*)(Wr + (d0 + i) * 8 + 4);
            part[0] += xs[i] * w0.x; part[1] += xs[i] * w0.y;
            part[2] += xs[i] * w0.z; part[3] += xs[i] * w0.w;
            part[4] += xs[i] * w1.x; part[5] += xs[i] * w1.y;
            part[6] += xs[i] * w1.z; part[7] += xs[i] * w1.w;
        }
    }
#pragma unroll
    for (int m = 32; m > 0; m >>= 1)
#pragma unroll
        for (int e = 0; e < 8; ++e) part[e] += __shfl_xor(part[e], m, 64);
    if (lane == 0) {
        float l[8];
#pragma unroll
        for (int e = 0; e < 8; ++e) l[e] = part[e] + br[e];
        int i1 = 0;
#pragma unroll
        for (int e = 1; e < 8; ++e) if (l[e] > l[i1]) i1 = e;   // first-index tiebreak
        int i2 = (i1 == 0) ? 1 : 0;
#pragma unroll
        for (int e = 0; e < 8; ++e) if (e != i1 && l[e] > l[i2]) i2 = e;
        const float e2 = expf(l[i2] - l[i1]);
        const float inv = 1.f / (1.f + e2);
        top_idx[t * 2 + 0] = i1;  gates[t * 2 + 0] = inv;
        top_idx[t * 2 + 1] = i2;  gates[t * 2 + 1] = e2 * inv;
        atomicAdd(&counts[i1], 1);
        atomicAdd(&counts[i2], 1);
    }
}

// ---------------- tiny scan: counts -> offs, init cursor --------------------------
__global__ void scan_kernel(const int* __restrict__ counts, int* __restrict__ offs,
                            int* __restrict__ cursor) {
    if (threadIdx.x == 0) {
        int s = 0;
        for (int e = 0; e < 8; ++e) { offs[e] = s; cursor[e] = s; s += counts[e]; }
        offs[8] = s;
    }
}

// ---------------- fill + gather fused: block per token ---------------------------
__global__ __launch_bounds__(256) void fillgather_kernel(
    const float* __restrict__ x, const int* __restrict__ top_idx,
    int* __restrict__ cursor, int* __restrict__ slotof, u16* __restrict__ Xg) {
    const int t = blockIdx.x;
    __shared__ int ps[2];
    if (threadIdx.x < 2) {
        const int e = top_idx[t * 2 + threadIdx.x];
        const int p = atomicAdd(&cursor[e], 1);
        ps[threadIdx.x] = p;
        slotof[t * 2 + threadIdx.x] = p;
    }
    __syncthreads();
    const int p0 = ps[0], p1 = ps[1];
    const int d = threadIdx.x * 4;
    const float4 v = *(const float4*)(x + (size_t)t * DMODEL + d);
    ushort4 o;
    o.x = f2bf(v.x); o.y = f2bf(v.y); o.z = f2bf(v.z); o.w = f2bf(v.w);
    *(ushort4*)(Xg + (size_t)p0 * DMODEL + d) = o;
    *(ushort4*)(Xg + (size_t)p1 * DMODEL + d) = o;
}

// ---------------- merged transpose + fp32->bf16 for BOTH weight tensors ----------
__global__ __launch_bounds__(256) void transpose_convert_kernel(
    const float* __restrict__ W1, u16* __restrict__ W1T,
    const float* __restrict__ W2, u16* __restrict__ W2T) {
    __shared__ float tile[64][65];
    const int t = blockIdx.x;
    const float* src; u16* dst; int R, C, r0, c0;
    if (t < 8192) {
        const int e = t >> 10, rem = t & 1023;
        R = 1024; C = 4096;
        r0 = (rem >> 6) * 64; c0 = (rem & 63) * 64;
        src = W1 + (size_t)e * R * C;
        dst = W1T + (size_t)e * R * C;
    } else {
        const int e = (t - 8192) >> 10, rem = (t - 8192) & 1023;
        R = 4096; C = 1024;
        r0 = (rem >> 4) * 64; c0 = (rem & 15) * 64;
        src = W2 + (size_t)e * R * C;
        dst = W2T + (size_t)e * R * C;
    }
    const int tr = threadIdx.x >> 4;
    const int tc4 = (threadIdx.x & 15) * 4;
#pragma unroll
    for (int i = 0; i < 4; ++i) {
        const int r = tr + i * 16;
        const float4 v = *(const float4*)(src + (size_t)(r0 + r) * C + c0 + tc4);
        tile[r][tc4 + 0] = v.x; tile[r][tc4 + 1] = v.y;
        tile[r][tc4 + 2] = v.z; tile[r][tc4 + 3] = v.w;
    }
    __syncthreads();
#pragma unroll
    for (int i = 0; i < 4; ++i) {
        const int rr = tr + i * 16;
        ushort4 o;
        o.x = f2bf(tile[tc4 + 0][rr]);
        o.y = f2bf(tile[tc4 + 1][rr]);
        o.z = f2bf(tile[tc4 + 2][rr]);
        o.w = f2bf(tile[tc4 + 3][rr]);
        *(ushort4*)(dst + (size_t)(c0 + rr) * R + r0 + tc4) = o;
    }
}

// ---------------- grouped GEMM, 256x256, 64KB ring, READ-AHEAD phases ------------
// ROUND 14: every MFMA consumes fragments ds_read >=1 phase earlier (tail-reads
// after each phase's MFMA issue). Phase = {BAR; stage; MFMA(pre-read frags);
// tail-reads(next phase); vm}. WAR safe: MFMA issues before the tail read that
// overwrites its operand regs; RAW via compiler lgkm (post-BAR, typically
// drained). Pre-BAR in-flight ds_reads vs post-BAR gload_lds writes to the
// same slot are ordered by the in-order LDS queue (same exposure as the
// verified m201 template).
// Ring (1 tile = 4 half-slots, 64KB -> 2 blocks/CU):
//   reads:  B1(t)@ph1-tail, A1(t)@ph2-tail, A0(t+1)+B0(t+1)@ph4-tail
//   stages: A0(t+1)@ph1, B0+B1(t+1)@ph2, A1(t+1)@ph3  (all >=1 BAR after the
//           slot's last read-issue)
//   waits:  vm2@ph1-end (A1 t: 3-phase lead), vm4@ph3-end (A0,B0 t+1: 3-phase),
//           vm2@ph4-end (B1 t+1: 3-phase). Last tile: vm0 fallbacks.
// T2 both-sides swizzle (0 conflicts), T5 setprio. Split-K partials:
// kh=0 -> Y0, kh>=1 -> Y1 + (kh-1)*YSTR.
template<int KTOT, int NTOT, int KH, int GM, bool GELU>
__global__ __launch_bounds__(512, 2) void gemm4ph_kernel(
    const u16* __restrict__ Amat, const u16* __restrict__ Bmat,
    const float* __restrict__ bias,
    u16* __restrict__ Y0, u16* __restrict__ Y1,
    const int* __restrict__ offs, const int* __restrict__ counts) {
    constexpr int J  = KTOT / (KH * 64);   // K-tiles per block
    constexpr int NT = NTOT / 256;

    int bid = blockIdx.x;
    const int e  = bid & 7;   bid >>= 3;
    const int kh = bid % KH;  bid /= KH;
    const int tn = bid % NT;  bid /= NT;
    const int tm0 = bid;                   // 0..GM-1
    const int cnt = counts[e];
    if (tm0 * 256 >= cnt) return;
    const int pend  = offs[e] + cnt;
    const int nbase = tn * 256;
    const int k0 = kh * (J * 64);
    u16* __restrict__ Cmat = (kh == 0) ? Y0 : (Y1 + (size_t)(kh - 1) * YSTR);

    __shared__ __align__(16) u16 As[2][128 * 64];   // A half-slots
    __shared__ __align__(16) u16 Bs[2][128 * 64];   // B half-slots

    const int tid = threadIdx.x;
    const int lane = tid & 63, wid = tid >> 6;
    const int wr = (wid >> 2) * 64;      // row offset within 128-row half
    const int wc = (wid & 3) * 32;       // col offset within 128-col half
    const int fr = lane & 15, fg = lane >> 4;
    const int rsw = (fr & 7) * 8;        // read-side XOR (elements)

    const int srow = tid >> 3;
    const int scol = 8 * ((tid & 7) ^ ((tid >> 3) & 7));
    const u16* Bpt = Bmat + (size_t)e * NTOT * KTOT
                          + (size_t)(nbase + srow) * KTOT + k0 + scol;

    float bv[2][2];
#pragma unroll
    for (int q = 0; q < 2; ++q)
#pragma unroll
        for (int n = 0; n < 2; ++n)
            bv[q][n] = GELU ? bias[e * NTOT + nbase + q * 128 + wc + n * 16 + fr] : 0.f;

    for (int tm = tm0; tm * 256 < cnt; tm += GM) {
        const int pbase = offs[e] + tm * 256;
        const u16* Apt = Amat + (size_t)(pbase + srow) * KTOT + k0 + scol;

        f32x4 acc[2][2][4][2];
#pragma unroll
        for (int qm = 0; qm < 2; ++qm)
#pragma unroll
            for (int qn = 0; qn < 2; ++qn)
#pragma unroll
                for (int m = 0; m < 4; ++m)
#pragma unroll
                    for (int n = 0; n < 2; ++n)
                        acc[qm][qn][m][n] = (f32x4){0.f, 0.f, 0.f, 0.f};

        bf16x8 aA[4][2], b0[2][2], b1[2][2];   // aA holds A0 then A1 per tile

        auto stgA = [&](int h, int tile) {
#pragma unroll
            for (int i = 0; i < 2; ++i)
                __builtin_amdgcn_global_load_lds(
                    (const __attribute__((address_space(1))) void*)
                        (Apt + ((size_t)tile << 6) + (size_t)(h * 128 + 64 * i) * KTOT),
                    (__attribute__((address_space(3))) void*)(&As[h][(size_t)(tid + 512 * i) * 8]),
                    16, 0, 0);
        };
        auto stgB = [&](int h, int tile) {
#pragma unroll
            for (int i = 0; i < 2; ++i)
                __builtin_amdgcn_global_load_lds(
                    (const __attribute__((address_space(1))) void*)
                        (Bpt + ((size_t)tile << 6) + (size_t)(h * 128 + 64 * i) * KTOT),
                    (__attribute__((address_space(3))) void*)(&Bs[h][(size_t)(tid + 512 * i) * 8]),
                    16, 0, 0);
        };
        auto rdA = [&](int h) {
#pragma unroll
            for (int m = 0; m < 4; ++m)
#pragma unroll
                for (int kc = 0; kc < 2; ++kc)
                    aA[m][kc] = *(const bf16x8*)(&As[h][
                        (wr + m * 16 + fr) * 64 + ((kc * 32 + fg * 8) ^ rsw)]);
        };
        auto rdB = [&](bf16x8 (&dst)[2][2], int h) {
#pragma unroll
            for (int n = 0; n < 2; ++n)
#pragma unroll
                for (int kc = 0; kc < 2; ++kc)
                    dst[n][kc] = *(const bf16x8*)(&Bs[h][
                        (wc + n * 16 + fr) * 64 + ((kc * 32 + fg * 8) ^ rsw)]);
        };
        auto mma = [&](int qm, int qn, const bf16x8 (&bb)[2][2]) {
            __builtin_amdgcn_s_setprio(1);
#pragma unroll
            for (int kc = 0; kc < 2; ++kc)
#pragma unroll
                for (int m = 0; m < 4; ++m)
#pragma unroll
                    for (int n = 0; n < 2; ++n)
                        acc[qm][qn][m][n] = __builtin_amdgcn_mfma_f32_16x16x32_bf16(
                            aA[m][kc], bb[n][kc], acc[qm][qn][m][n], 0, 0, 0);
            __builtin_amdgcn_s_setprio(0);
        };
        auto bar = [&]() {
            asm volatile("" ::: "memory");
            __builtin_amdgcn_s_barrier();
            asm volatile("" ::: "memory");
        };

        __syncthreads();   // defensive: all waves past previous item's LDS use
        // prologue: stage tile0's 4 halves; read A0,B0 fragments pre-loop.
        stgA(0, 0); stgB(0, 0); stgB(1, 0); stgA(1, 0);
        vmw<4>();                          // A0,B0 landed (own); BAR publishes
        bar();
        rdA(0); rdB(b0, 0);                // ph1(0) operands, one phase ahead
        asm volatile("s_waitcnt lgkmcnt(0)" ::: "memory");  // drain before any overwrite
        __builtin_amdgcn_sched_barrier(0);

#pragma unroll 1
        for (int t = 0; t < J; ++t) {
            const bool s1 = (t + 1 < J);
            // ph1: mma(A0,B0) pre-read; stage A0(t+1); tail-read B1(t)
            bar();
            if (s1) stgA(0, t + 1);
            mma(0, 0, b0);
            rdB(b1, 1);
            if (s1) vmw<2>(); else vmw<0>();     // A1(t) published at next BAR
            // ph2: mma(A0,B1); stage B0,B1(t+1); tail-read A1(t)
            bar();
            if (s1) { stgB(0, t + 1); stgB(1, t + 1); }
            mma(0, 1, b1);
            rdA(1);
            // ph3: mma(A1,B1); stage A1(t+1)
            bar();
            if (s1) stgA(1, t + 1);
            mma(1, 1, b1);
            if (s1) vmw<4>(); else vmw<0>();     // A0,B0(t+1) published at next BAR
            // ph4: mma(A1,B0); tail-read A0,B0(t+1)
            bar();
            mma(1, 0, b0);
            if (s1) { rdA(0); rdB(b0, 0); }
            if (s1) vmw<2>(); else vmw<0>();     // B1(t+1) published at next BAR
        }

        // epilogue (registers only)
#pragma unroll
        for (int qm = 0; qm < 2; ++qm) {
#pragma unroll
            for (int m = 0; m < 4; ++m) {
#pragma unroll
                for (int r = 0; r < 4; ++r) {
                    const int p = pbase + qm * 128 + wr + m * 16 + fg * 4 + r;
                    if (p >= pend) continue;
#pragma unroll
                    for (int qn = 0; qn < 2; ++qn) {
#pragma unroll
                        for (int n = 0; n < 2; ++n) {
                            const int col = nbase + qn * 128 + wc + n * 16 + fr;
                            float v = acc[qm][qn][m][n][r];
                            if (GELU) v = fast_gelu(v + bv[qn][n]);
                            Cmat[(size_t)p * NTOT + col] = f2bf(v);
                        }
                    }
                }
            }
        }
    }
}

// ------- combine: out[t] = sum_k g_k * (sum_kh y[kh][p_k] + b2[e_k]) -------------
__global__ void combine_kernel(const u16* __restrict__ Y0, const u16* __restrict__ Y1,
                               const float* __restrict__ b2,
                               const int* __restrict__ top_idx, const float* __restrict__ gates,
                               const int* __restrict__ slotof, float* __restrict__ out) {
    const int t = blockIdx.x;
    const int d = threadIdx.x * 4;
    float4 o = {0.f, 0.f, 0.f, 0.f};
#pragma unroll
    for (int k = 0; k < 2; ++k) {
        const int ee = top_idx[t * 2 + k];
        const float g = gates[t * 2 + k];
        const int p = slotof[t * 2 + k];
        const float4 bb = *(const float4*)(b2 + ee * DMODEL + d);
        float sx = bb.x, sy = bb.y, sz = bb.z, sw = bb.w;
        {
            const ushort4 y = *(const ushort4*)(Y0 + (size_t)p * DMODEL + d);
            sx += bf2f(y.x); sy += bf2f(y.y); sz += bf2f(y.z); sw += bf2f(y.w);
        }
#pragma unroll
        for (int kh = 0; kh < 3; ++kh) {
            const ushort4 y = *(const ushort4*)(Y1 + (size_t)kh * YSTR + (size_t)p * DMODEL + d);
            sx += bf2f(y.x); sy += bf2f(y.y); sz += bf2f(y.z); sw += bf2f(y.w);
        }
        o.x += g * sx; o.y += g * sy; o.z += g * sz; o.w += g * sw;
    }
    *(float4*)(out + (size_t)t * DMODEL + d) = o;
}

extern "C" void kernel_launch(void* const* d_in, const int* in_sizes, int n_in,
                              void* d_out, int out_size, void* d_ws, size_t ws_size,
                              hipStream_t stream) {
    const float* x  = (const float*)d_in[0];
    const float* Wr = (const float*)d_in[1];
    const float* br = (const float*)d_in[2];
    const float* W1 = (const float*)d_in[3];
    const float* b1 = (const float*)d_in[4];
    const float* W2 = (const float*)d_in[5];
    const float* b2 = (const float*)d_in[6];
    float* out = (float*)d_out;

    // workspace carve (all 16B aligned)
    char* w = (char*)d_ws;
    int*   counts   = (int*)(w + 0);          // 32 B
    int*   cursor   = (int*)(w + 32);         // 32 B
    int*   offs     = (int*)(w + 64);         // 64 B
    int*   top_idx  = (int*)(w + 1024);                   // 32 KB
    float* gates    = (float*)(w + 1024 + 32768);         // 32 KB
    int*   slotof   = (int*)(w + 1024 + 65536);           // 32 KB
    u16*   Xg       = (u16*)(w + 1024 + 65536 + 32768);
    u16*   hbuf     = Xg + (size_t)ROWS_PAD * DMODEL;
    u16*   W1T      = hbuf + (size_t)ROWS_PAD * DFF;
    u16*   W2T      = W1T + (size_t)NEXP * DFF * DMODEL;
    u16*   ybuf0    = Xg;    // split-K part 0: Xg dead after ffn1 (17 MB)
    u16*   ybuf123  = W1T;   // parts 1..3: W1T dead after ffn1 (3x17 MB <= 64 MB)
    const size_t need = (size_t)(1024 + 65536 + 32768)
        + (size_t)ROWS_PAD * DMODEL * 2 + (size_t)ROWS_PAD * DFF * 2
        + (size_t)NEXP * DFF * DMODEL * 4;
    if (ws_size < need) return;  // fail loudly (absmax) rather than corrupt memory

    hipMemsetAsync(d_ws, 0, 64, stream);  // counts + cursor

    // merged weight transpose/convert: W1 -> W1T and W2 -> W2T in one launch
    transpose_convert_kernel<<<16384, 256, 0, stream>>>(W1, W1T, W2, W2T);

    router_kernel<<<T_TOK, 64, 0, stream>>>(x, Wr, br, top_idx, gates, counts);
    scan_kernel<<<1, 64, 0, stream>>>(counts, offs, cursor);
    fillgather_kernel<<<T_TOK, 256, 0, stream>>>(x, top_idx, cursor, slotof, Xg);

    // ffn1: h = gelu(Xg @ W1T^T + b1); KTOT=1024, J=16, KH=1, GM=4
    // grid = GM(4) x KH(1) x NT(16) x E(8) = 512 -> 2 blocks/CU
    gemm4ph_kernel<1024, 4096, 1, 4, true><<<512, 512, 0, stream>>>(
        Xg, W1T, b1, hbuf, nullptr, offs, counts);
    // ffn2: y = h @ W2T^T; KTOT=4096, split-K=4 (J=16 each), GM=4
    // grid = GM(4) x KH(4) x NT(4) x E(8) = 512 -> 2 blocks/CU
    gemm4ph_kernel<4096, 1024, 4, 4, false><<<512, 512, 0, stream>>>(
        hbuf, W2T, nullptr, ybuf0, ybuf123, offs, counts);
    // combine: one block per token, sums 4 split-K partials + bias
    combine_kernel<<<T_TOK, 256, 0, stream>>>(ybuf0, ybuf123, b2, top_idx, gates, slotof, out);
}

// Round 15
// 367.815 us; speedup vs baseline: 1.2366x; 1.2366x over previous
//
#include <hip/hip_runtime.h>
#include <hip/hip_bf16.h>

#define T_TOK 4096
#define DMODEL 1024
#define DFF 4096
#define NEXP 8
#define ROWS_TOT 8192      // T_TOK * TOPK, fixed
#define ROWS_PAD 8448      // + 256 pad rows for BM=256 tile overrun
#define YSTR ((size_t)ROWS_PAD * DMODEL)

typedef __bf16 bf16x8 __attribute__((ext_vector_type(8)));
typedef float f32x4 __attribute__((ext_vector_type(4)));
typedef unsigned short u16;

__device__ __forceinline__ u16 f2bf(float f) {
    __hip_bfloat16 b = __float2bfloat16(f);
    return __builtin_bit_cast(u16, b);
}
__device__ __forceinline__ float bf2f(u16 u) {
    unsigned v = (unsigned)u << 16;
    return __builtin_bit_cast(float, v);
}

// exact-erf GELU via Abramowitz-Stegun 7.1.26 (|eps|<=1.5e-7 << bf16 rounding of h)
__device__ __forceinline__ float fast_gelu(float v) {
    const float x = v * 0.70710678118654752f;
    const float ax = fabsf(x);
    const float t = 1.f / fmaf(0.3275911f, ax, 1.f);
    float p = fmaf(1.061405429f, t, -1.453152027f);
    p = fmaf(p, t, 1.421413741f);
    p = fmaf(p, t, -0.284496736f);
    p = fmaf(p, t, 0.254829592f);
    p *= t;
    const float e = __expf(-ax * ax);
    float erfv = fmaf(-p, e, 1.f);
    erfv = copysignf(erfv, x);
    return 0.5f * v * (1.f + erfv);
}

// ---------------- router: 4 tokens per block (wave per token) --------------------
// ROUND 15: 1024 blocks x 256 threads (vs 4096 x 64): proper launch shape for a
// tiny kernel; per-block LDS count aggregation -> 8 global atomics per block.
__global__ __launch_bounds__(256) void router_kernel(
    const float* __restrict__ x, const float* __restrict__ Wr,
    const float* __restrict__ br, int* __restrict__ top_idx,
    float* __restrict__ gates, int* __restrict__ counts) {
    const int wv = threadIdx.x >> 6;           // wave = token within block
    const int t = blockIdx.x * 4 + wv;
    const int lane = threadIdx.x & 63;
    __shared__ int lcnt[8];
    if (threadIdx.x < 8) lcnt[threadIdx.x] = 0;
    __syncthreads();
    float part[8];
#pragma unroll
    for (int e = 0; e < 8; ++e) part[e] = 0.f;
#pragma unroll
    for (int j = 0; j < 4; ++j) {
        const int d0 = j * 256 + lane * 4;
        const float4 xv = *(const float4*)(x + (size_t)t * DMODEL + d0);
        const float xs[4] = {xv.x, xv.y, xv.z, xv.w};
#pragma unroll
        for (int i = 0; i < 4; ++i) {
            const float4 w0 = *(const float4*)(Wr + (d0 + i) * 8);
            const float4 w1 = *(const float4*)(Wr + (d0 + i) * 8 + 4);
            part[0] += xs[i] * w0.x; part[1] += xs[i] * w0.y;
            part[2] += xs[i] * w0.z; part[3] += xs[i] * w0.w;
            part[4] += xs[i] * w1.x; part[5] += xs[i] * w1.y;
            part[6] += xs[i] * w1.z; part[7] += xs[i] * w1.w;
        }
    }
#pragma unroll
    for (int m = 32; m > 0; m >>= 1)
#pragma unroll
        for (int e = 0; e < 8; ++e) part[e] += __shfl_xor(part[e], m, 64);
    if (lane == 0) {
        float l[8];
#pragma unroll
        for (int e = 0; e < 8; ++e) l[e] = part[e] + br[e];
        int i1 = 0;
#pragma unroll
        for (int e = 1; e < 8; ++e) if (l[e] > l[i1]) i1 = e;   // first-index tiebreak
        int i2 = (i1 == 0) ? 1 : 0;
#pragma unroll
        for (int e = 0; e < 8; ++e) if (e != i1 && l[e] > l[i2]) i2 = e;
        const float e2 = expf(l[i2] - l[i1]);
        const float inv = 1.f / (1.f + e2);
        top_idx[t * 2 + 0] = i1;  gates[t * 2 + 0] = inv;
        top_idx[t * 2 + 1] = i2;  gates[t * 2 + 1] = e2 * inv;
        atomicAdd(&lcnt[i1], 1);
        atomicAdd(&lcnt[i2], 1);
    }
    __syncthreads();
    if (threadIdx.x < 8 && lcnt[threadIdx.x] > 0)
        atomicAdd(&counts[threadIdx.x], lcnt[threadIdx.x]);
}

// ---------------- tiny scan: counts -> offs, init cursor --------------------------
__global__ void scan_kernel(const int* __restrict__ counts, int* __restrict__ offs,
                            int* __restrict__ cursor) {
    if (threadIdx.x == 0) {
        int s = 0;
        for (int e = 0; e < 8; ++e) { offs[e] = s; cursor[e] = s; s += counts[e]; }
        offs[8] = s;
    }
}

// ---------------- fill + gather fused: block per token ---------------------------
__global__ __launch_bounds__(256) void fillgather_kernel(
    const float* __restrict__ x, const int* __restrict__ top_idx,
    int* __restrict__ cursor, int* __restrict__ slotof, u16* __restrict__ Xg) {
    const int t = blockIdx.x;
    __shared__ int ps[2];
    if (threadIdx.x < 2) {
        const int e = top_idx[t * 2 + threadIdx.x];
        const int p = atomicAdd(&cursor[e], 1);
        ps[threadIdx.x] = p;
        slotof[t * 2 + threadIdx.x] = p;
    }
    __syncthreads();
    const int p0 = ps[0], p1 = ps[1];
    const int d = threadIdx.x * 4;
    const float4 v = *(const float4*)(x + (size_t)t * DMODEL + d);
    ushort4 o;
    o.x = f2bf(v.x); o.y = f2bf(v.y); o.z = f2bf(v.z); o.w = f2bf(v.w);
    *(ushort4*)(Xg + (size_t)p0 * DMODEL + d) = o;
    *(ushort4*)(Xg + (size_t)p1 * DMODEL + d) = o;
}

// ---------------- merged transpose + fp32->bf16 for BOTH weight tensors ----------
__global__ __launch_bounds__(256) void transpose_convert_kernel(
    const float* __restrict__ W1, u16* __restrict__ W1T,
    const float* __restrict__ W2, u16* __restrict__ W2T) {
    __shared__ float tile[64][65];
    const int t = blockIdx.x;
    const float* src; u16* dst; int R, C, r0, c0;
    if (t < 8192) {
        const int e = t >> 10, rem = t & 1023;
        R = 1024; C = 4096;
        r0 = (rem >> 6) * 64; c0 = (rem & 63) * 64;
        src = W1 + (size_t)e * R * C;
        dst = W1T + (size_t)e * R * C;
    } else {
        const int e = (t - 8192) >> 10, rem = (t - 8192) & 1023;
        R = 4096; C = 1024;
        r0 = (rem >> 4) * 64; c0 = (rem & 15) * 64;
        src = W2 + (size_t)e * R * C;
        dst = W2T + (size_t)e * R * C;
    }
    const int tr = threadIdx.x >> 4;
    const int tc4 = (threadIdx.x & 15) * 4;
#pragma unroll
    for (int i = 0; i < 4; ++i) {
        const int r = tr + i * 16;
        const float4 v = *(const float4*)(src + (size_t)(r0 + r) * C + c0 + tc4);
        tile[r][tc4 + 0] = v.x; tile[r][tc4 + 1] = v.y;
        tile[r][tc4 + 2] = v.z; tile[r][tc4 + 3] = v.w;
    }
    __syncthreads();
#pragma unroll
    for (int i = 0; i < 4; ++i) {
        const int rr = tr + i * 16;
        ushort4 o;
        o.x = f2bf(tile[tc4 + 0][rr]);
        o.y = f2bf(tile[tc4 + 1][rr]);
        o.z = f2bf(tile[tc4 + 2][rr]);
        o.w = f2bf(tile[tc4 + 3][rr]);
        *(ushort4*)(dst + (size_t)(c0 + rr) * R + r0 + tc4) = o;
    }
}

// ---------------- grouped GEMM, 256x256 tile, 64KB LDS / 2 blocks-per-CU ---------
// ROUND 15: byte-identical to the round-13 kernel (best measured: 123 us,
// VGPR 124, no spill). Ring: As[2]/Bs[2] half-slots (64KB -> 2 blocks/CU at
// __launch_bounds__(512,2); hipcc 2nd arg = min BLOCKS/CU). Per tile t:
// ph1 (A0,B0), ph2 (A0,B1), ph3 (A1,B1), ph4 (A1,B0 regs). Stage t+1:
// A0@ph2, B0+B1@ph3, A1@ph4. Waits: vm2@ph1-end (B1), vm2@ph2-end (A1),
// vm4@ph4-end (next A0,B0). T2 both-sides swizzle (0 conflicts), T5 setprio.
// Split-K partials: kh=0 -> Y0, kh>=1 -> Y1 + (kh-1)*YSTR.
template<int KTOT, int NTOT, int KH, int GM, bool GELU>
__global__ __launch_bounds__(512, 2) void gemm4ph_kernel(
    const u16* __restrict__ Amat, const u16* __restrict__ Bmat,
    const float* __restrict__ bias,
    u16* __restrict__ Y0, u16* __restrict__ Y1,
    const int* __restrict__ offs, const int* __restrict__ counts) {
    constexpr int J  = KTOT / (KH * 64);   // K-tiles per block
    constexpr int NT = NTOT / 256;

    int bid = blockIdx.x;
    const int e  = bid & 7;   bid >>= 3;
    const int kh = bid % KH;  bid /= KH;
    const int tn = bid % NT;  bid /= NT;
    const int tm0 = bid;                   // 0..GM-1
    const int cnt = counts[e];
    if (tm0 * 256 >= cnt) return;
    const int pend  = offs[e] + cnt;
    const int nbase = tn * 256;
    const int k0 = kh * (J * 64);
    u16* __restrict__ Cmat = (kh == 0) ? Y0 : (Y1 + (size_t)(kh - 1) * YSTR);

    __shared__ __align__(16) u16 As[2][128 * 64];   // A halves (slots)
    __shared__ __align__(16) u16 Bs[2][128 * 64];   // B halves (slots)

    const int tid = threadIdx.x;
    const int lane = tid & 63, wid = tid >> 6;
    const int wr = (wid >> 2) * 64;      // row offset within 128-row half
    const int wc = (wid & 3) * 32;       // col offset within 128-col half
    const int fr = lane & 15, fg = lane >> 4;
    const int rsw = (fr & 7) * 8;        // read-side XOR (elements)

    const int srow = tid >> 3;
    const int scol = 8 * ((tid & 7) ^ ((tid >> 3) & 7));
    const u16* Bpt = Bmat + (size_t)e * NTOT * KTOT
                          + (size_t)(nbase + srow) * KTOT + k0 + scol;

    float bv[2][2];
#pragma unroll
    for (int q = 0; q < 2; ++q)
#pragma unroll
        for (int n = 0; n < 2; ++n)
            bv[q][n] = GELU ? bias[e * NTOT + nbase + q * 128 + wc + n * 16 + fr] : 0.f;

    for (int tm = tm0; tm * 256 < cnt; tm += GM) {
        const int pbase = offs[e] + tm * 256;
        const u16* Apt = Amat + (size_t)(pbase + srow) * KTOT + k0 + scol;

        f32x4 acc[2][2][4][2];
#pragma unroll
        for (int qm = 0; qm < 2; ++qm)
#pragma unroll
            for (int qn = 0; qn < 2; ++qn)
#pragma unroll
                for (int m = 0; m < 4; ++m)
#pragma unroll
                    for (int n = 0; n < 2; ++n)
                        acc[qm][qn][m][n] = (f32x4){0.f, 0.f, 0.f, 0.f};

        bf16x8 aA[4][2], b0[2][2], b1[2][2];   // aA reused for A1

        auto stgA = [&](int h, int tile) {
#pragma unroll
            for (int i = 0; i < 2; ++i)
                __builtin_amdgcn_global_load_lds(
                    (const __attribute__((address_space(1))) void*)
                        (Apt + ((size_t)tile << 6) + (size_t)(h * 128 + 64 * i) * KTOT),
                    (__attribute__((address_space(3))) void*)(&As[h][(size_t)(tid + 512 * i) * 8]),
                    16, 0, 0);
        };
        auto stgB = [&](int h, int tile) {
#pragma unroll
            for (int i = 0; i < 2; ++i)
                __builtin_amdgcn_global_load_lds(
                    (const __attribute__((address_space(1))) void*)
                        (Bpt + ((size_t)tile << 6) + (size_t)(h * 128 + 64 * i) * KTOT),
                    (__attribute__((address_space(3))) void*)(&Bs[h][(size_t)(tid + 512 * i) * 8]),
                    16, 0, 0);
        };
        auto rdA = [&](int h) {
#pragma unroll
            for (int m = 0; m < 4; ++m)
#pragma unroll
                for (int kc = 0; kc < 2; ++kc)
                    aA[m][kc] = *(const bf16x8*)(&As[h][
                        (wr + m * 16 + fr) * 64 + ((kc * 32 + fg * 8) ^ rsw)]);
        };
        auto rdB = [&](bf16x8 (&dst)[2][2], int h) {
#pragma unroll
            for (int n = 0; n < 2; ++n)
#pragma unroll
                for (int kc = 0; kc < 2; ++kc)
                    dst[n][kc] = *(const bf16x8*)(&Bs[h][
                        (wc + n * 16 + fr) * 64 + ((kc * 32 + fg * 8) ^ rsw)]);
        };
        auto mma = [&](int qm, int qn, const bf16x8 (&bb)[2][2]) {
            __builtin_amdgcn_s_setprio(1);
#pragma unroll
            for (int kc = 0; kc < 2; ++kc)
#pragma unroll
                for (int m = 0; m < 4; ++m)
#pragma unroll
                    for (int n = 0; n < 2; ++n)
                        acc[qm][qn][m][n] = __builtin_amdgcn_mfma_f32_16x16x32_bf16(
                            aA[m][kc], bb[n][kc], acc[qm][qn][m][n], 0, 0, 0);
            __builtin_amdgcn_s_setprio(0);
        };
        auto bar = [&]() {
            asm volatile("" ::: "memory");
            __builtin_amdgcn_s_barrier();
            asm volatile("" ::: "memory");
        };

        // prologue: tile0's four halves; wait A0,B0 landed (leave B1,A1 in flight)
        stgA(0, 0); stgB(0, 0); stgB(1, 0); stgA(1, 0);
        asm volatile("s_waitcnt vmcnt(4)" ::: "memory");

#pragma unroll 1
        for (int t = 0; t < J; ++t) {
            const bool s1 = (t + 1 < J);
            // ph1: Q(0,0) uses A0,B0
            bar();
            rdA(0); rdB(b0, 0);
            mma(0, 0, b0);
            asm volatile("s_waitcnt vmcnt(2)" ::: "memory");   // B1(t) landed
            // ph2: Q(0,1) uses A0,B1; stage A0(t+1) (A0 dead after ph1)
            bar();
            rdB(b1, 1);
            if (s1) stgA(0, t + 1);
            mma(0, 1, b1);
            asm volatile("s_waitcnt vmcnt(2)" ::: "memory");   // A1(t) landed
            // ph3: Q(1,1) uses A1,B1; stage B0,B1(t+1) (dead after ph1/ph2)
            bar();
            rdA(1);
            if (s1) { stgB(0, t + 1); stgB(1, t + 1); }
            mma(1, 1, b1);
            // ph4: Q(1,0) uses A1,B0 (registers only); stage A1(t+1)
            bar();
            if (s1) stgA(1, t + 1);
            mma(1, 0, b0);
            asm volatile("s_waitcnt vmcnt(4)" ::: "memory");   // next A0,B0 landed
        }

        // epilogue (registers only; all LDS reads drained before last bar)
#pragma unroll
        for (int qm = 0; qm < 2; ++qm) {
#pragma unroll
            for (int m = 0; m < 4; ++m) {
#pragma unroll
                for (int r = 0; r < 4; ++r) {
                    const int p = pbase + qm * 128 + wr + m * 16 + fg * 4 + r;
                    if (p >= pend) continue;
#pragma unroll
                    for (int qn = 0; qn < 2; ++qn) {
#pragma unroll
                        for (int n = 0; n < 2; ++n) {
                            const int col = nbase + qn * 128 + wc + n * 16 + fr;
                            float v = acc[qm][qn][m][n][r];
                            if (GELU) v = fast_gelu(v + bv[qn][n]);
                            Cmat[(size_t)p * NTOT + col] = f2bf(v);
                        }
                    }
                }
            }
        }
    }
}

// ------- combine: out[t] = sum_k g_k * (sum_kh y[kh][p_k] + b2[e_k]) -------------
__global__ void combine_kernel(const u16* __restrict__ Y0, const u16* __restrict__ Y1,
                               const float* __restrict__ b2,
                               const int* __restrict__ top_idx, const float* __restrict__ gates,
                               const int* __restrict__ slotof, float* __restrict__ out) {
    const int t = blockIdx.x;
    const int d = threadIdx.x * 4;
    float4 o = {0.f, 0.f, 0.f, 0.f};
#pragma unroll
    for (int k = 0; k < 2; ++k) {
        const int ee = top_idx[t * 2 + k];
        const float g = gates[t * 2 + k];
        const int p = slotof[t * 2 + k];
        const float4 bb = *(const float4*)(b2 + ee * DMODEL + d);
        float sx = bb.x, sy = bb.y, sz = bb.z, sw = bb.w;
        {
            const ushort4 y = *(const ushort4*)(Y0 + (size_t)p * DMODEL + d);
            sx += bf2f(y.x); sy += bf2f(y.y); sz += bf2f(y.z); sw += bf2f(y.w);
        }
#pragma unroll
        for (int kh = 0; kh < 3; ++kh) {
            const ushort4 y = *(const ushort4*)(Y1 + (size_t)kh * YSTR + (size_t)p * DMODEL + d);
            sx += bf2f(y.x); sy += bf2f(y.y); sz += bf2f(y.z); sw += bf2f(y.w);
        }
        o.x += g * sx; o.y += g * sy; o.z += g * sz; o.w += g * sw;
    }
    *(float4*)(out + (size_t)t * DMODEL + d) = o;
}

extern "C" void kernel_launch(void* const* d_in, const int* in_sizes, int n_in,
                              void* d_out, int out_size, void* d_ws, size_t ws_size,
                              hipStream_t stream) {
    const float* x  = (const float*)d_in[0];
    const float* Wr = (const float*)d_in[1];
    const float* br = (const float*)d_in[2];
    const float* W1 = (const float*)d_in[3];
    const float* b1 = (const float*)d_in[4];
    const float* W2 = (const float*)d_in[5];
    const float* b2 = (const float*)d_in[6];
    float* out = (float*)d_out;

    // workspace carve (all 16B aligned)
    char* w = (char*)d_ws;
    int*   counts   = (int*)(w + 0);          // 32 B
    int*   cursor   = (int*)(w + 32);         // 32 B
    int*   offs     = (int*)(w + 64);         // 64 B
    int*   top_idx  = (int*)(w + 1024);                   // 32 KB
    float* gates    = (float*)(w + 1024 + 32768);         // 32 KB
    int*   slotof   = (int*)(w + 1024 + 65536);           // 32 KB
    u16*   Xg       = (u16*)(w + 1024 + 65536 + 32768);
    u16*   hbuf     = Xg + (size_t)ROWS_PAD * DMODEL;
    u16*   W1T      = hbuf + (size_t)ROWS_PAD * DFF;
    u16*   W2T      = W1T + (size_t)NEXP * DFF * DMODEL;
    u16*   ybuf0    = Xg;    // split-K part 0: Xg dead after ffn1 (17 MB)
    u16*   ybuf123  = W1T;   // parts 1..3: W1T dead after ffn1 (3x17 MB <= 64 MB)
    const size_t need = (size_t)(1024 + 65536 + 32768)
        + (size_t)ROWS_PAD * DMODEL * 2 + (size_t)ROWS_PAD * DFF * 2
        + (size_t)NEXP * DFF * DMODEL * 4;
    if (ws_size < need) return;  // fail loudly (absmax) rather than corrupt memory

    hipMemsetAsync(d_ws, 0, 64, stream);  // counts + cursor

    // merged weight transpose/convert: W1 -> W1T and W2 -> W2T in one launch
    transpose_convert_kernel<<<16384, 256, 0, stream>>>(W1, W1T, W2, W2T);

    // router: 1024 blocks x 256 threads (4 tokens per block, wave per token)
    router_kernel<<<T_TOK / 4, 256, 0, stream>>>(x, Wr, br, top_idx, gates, counts);
    scan_kernel<<<1, 64, 0, stream>>>(counts, offs, cursor);
    fillgather_kernel<<<T_TOK, 256, 0, stream>>>(x, top_idx, cursor, slotof, Xg);

    // ffn1: h = gelu(Xg @ W1T^T + b1); KTOT=1024, J=16, KH=1, GM=4
    // grid = GM(4) x KH(1) x NT(16) x E(8) = 512 -> 2 blocks/CU
    gemm4ph_kernel<1024, 4096, 1, 4, true><<<512, 512, 0, stream>>>(
        Xg, W1T, b1, hbuf, nullptr, offs, counts);
    // ffn2: y = h @ W2T^T; KTOT=4096, split-K=4 (J=16 each), GM=4
    // grid = GM(4) x KH(4) x NT(4) x E(8) = 512 -> 2 blocks/CU
    gemm4ph_kernel<4096, 1024, 4, 4, false><<<512, 512, 0, stream>>>(
        hbuf, W2T, nullptr, ybuf0, ybuf123, offs, counts);
    // combine: one block per token, sums 4 split-K partials + bias
    combine_kernel<<<T_TOK, 256, 0, stream>>>(ybuf0, ybuf123, b2, top_idx, gates, slotof, out);
}